// Round 3
// baseline (302.660 us; speedup 1.0000x reference)
//
#include <hip/hip_runtime.h>

// KnotAttention MI355X — round 10: fp8 denominator pass + single-f16-gather pass.
//
// R9 post-mortem: occupancy 34->75% made it SLOWER (52.6->93.6us, requested-BW
// 2.43->1.37 TB/s, L2 misses 62->85.6 MB). The gather is miss-service-bound,
// not latency-bound. Levers: fewer bytes, better hit rate. REVERTED to R7's
// NPB=32 / 40KB / 4-blocks-per-CU operating point everywhere.
//
// R10: S[h][r] = sum of 100k exp terms -> fp8 input quantization averages out
// (S rel err ~1e-4, far below f16-path output error). Pass A gathers fp8 x
// (64 MB requested, 12.8 MB footprint -> better L2 hit) computing ONLY the
// softmax sums. Pass B does ONE f16 gather computing Q,K->e (f16-exact
// numerator), V, 1/S scale, and the output. Second f16 gather + eh eliminated.

#define N_NODES 100000
#define D 128
#define H 4
#define R 5
#define NPB 32
#define THREADS 256
#define NBLOCKS (N_NODES / NPB)   // 3125

typedef _Float16 half_t;
typedef __attribute__((ext_vector_type(8))) _Float16 f16x8;
typedef __attribute__((ext_vector_type(4))) float f32x4;
typedef __attribute__((ext_vector_type(2))) float f32x2;

typedef const __attribute__((address_space(1))) unsigned int* gp_t;
typedef __attribute__((address_space(3))) unsigned int* lp_t;

__device__ __forceinline__ void async_copy16(const void* g, void* l) {
    __builtin_amdgcn_global_load_lds((gp_t)g, (lp_t)l, 16, 0, 0);
}

// ---------------------------- fp8 e4m3 helpers ------------------------------
__device__ __forceinline__ unsigned enc1(float f) {
    float a = fabsf(f);
    a = fminf(a, 448.f);
    unsigned s = f < 0.f ? 0x80u : 0u;
    if (a < 0.015625f) {                         // subnormal region (< 2^-6)
        unsigned m = (unsigned)(int)rintf(a * 512.f);   // RNE
        return s | m;                            // m==8 naturally -> e=1,m=0
    }
    int E = (int)((__float_as_uint(a) >> 23) & 255) - 127;
    float sc = __uint_as_float((unsigned)(3 - E + 127) << 23);
    int m = (int)rintf(a * sc);                  // in [8,16], RNE
    if (m == 16) { m = 8; ++E; }
    return s | (unsigned)((E + 7) << 3) | (unsigned)(m - 8);
}

__device__ __forceinline__ unsigned enc_pk4(float a, float b, float c, float d) {
#if __has_builtin(__builtin_amdgcn_cvt_pk_fp8_f32)
    unsigned w = (unsigned)__builtin_amdgcn_cvt_pk_fp8_f32(a, b, 0, false);
    w = (unsigned)__builtin_amdgcn_cvt_pk_fp8_f32(c, d, (int)w, true);
    return w;
#else
    return enc1(a) | (enc1(b) << 8) | (enc1(c) << 16) | (enc1(d) << 24);
#endif
}

__device__ __forceinline__ f16x8 dec8(uint2 v) {
#if __has_builtin(__builtin_amdgcn_cvt_pk_f32_fp8)
    f32x2 p0 = __builtin_amdgcn_cvt_pk_f32_fp8(v.x, false);
    f32x2 p1 = __builtin_amdgcn_cvt_pk_f32_fp8(v.x, true);
    f32x2 p2 = __builtin_amdgcn_cvt_pk_f32_fp8(v.y, false);
    f32x2 p3 = __builtin_amdgcn_cvt_pk_f32_fp8(v.y, true);
    return (f16x8){(half_t)p0.x, (half_t)p0.y, (half_t)p1.x, (half_t)p1.y,
                   (half_t)p2.x, (half_t)p2.y, (half_t)p3.x, (half_t)p3.y};
#else
    f16x8 r;
#pragma unroll
    for (int i = 0; i < 8; ++i) {
        unsigned b = ((i < 4) ? (v.x >> (8 * i)) : (v.y >> (8 * (i - 4)))) & 0xffu;
        unsigned e = (b >> 3) & 15u, m = b & 7u;
        float mag = (e == 0) ? (float)m * 0.001953125f
                             : __uint_as_float(((e + 120u) << 23) | (m << 20));
        r[i] = (half_t)((b & 0x80u) ? -mag : mag);
    }
    return r;
#endif
}

// ------------- prep: weights -> A-frags, x -> f16 + fp8, zero sums ----------
__global__ void prep(const float* __restrict__ x,
                     const float* __restrict__ wq, const float* __restrict__ wk,
                     const float* __restrict__ wv,
                     half_t* __restrict__ xh, unsigned char* __restrict__ xq,
                     half_t* __restrict__ wph, float* __restrict__ sums_p)
{
    const int bid = blockIdx.x;
    const int t = threadIdx.x;
    if (bid < 44) {
        const float* src = (bid < 4) ? (wq + bid * 4096)
                         : (bid < 24) ? (wk + (bid - 4) * 4096)
                                      : (wv + (bid - 24) * 4096);
#pragma unroll
        for (int i = 0; i < 16; ++i) {
            int p = t * 16 + i;
            int j = p & 7, ln = (p >> 3) & 63, f = p >> 9;
            int kt = f & 3, mt = f >> 2;
            int d = kt * 32 + (ln >> 4) * 8 + j;
            int ko = mt * 16 + (ln & 15);
            wph[bid * 4096 + p] = (half_t)src[d * 32 + ko];
        }
    } else {
        if (bid == 44) {
            for (int i = t; i < 1280; i += THREADS) sums_p[i] = 0.f;
        }
        const int total = N_NODES * D / 8;
        const int nb = gridDim.x - 44;
        for (int i = (bid - 44) * THREADS + t; i < total; i += nb * THREADS) {
            const float4* s = (const float4*)x + (size_t)i * 2;
            float4 a = s[0], b = s[1];
            f16x8 h8 = {(half_t)a.x, (half_t)a.y, (half_t)a.z, (half_t)a.w,
                        (half_t)b.x, (half_t)b.y, (half_t)b.z, (half_t)b.w};
            *((f16x8*)xh + i) = h8;
            uint2 t8;
            t8.x = enc_pk4(a.x, a.y, a.z, a.w);
            t8.y = enc_pk4(b.x, b.y, b.z, b.w);
            ((uint2*)xq)[i] = t8;
        }
    }
}

// --------- f16 stage: 5 slot-tiles, 256-B rows, 10 DMA instrs/wave ----------
// slot r at r*8192; 16-B quad kq of row stored at kq^(row&7) (swizzle folded
// into the GLOBAL address; LDS dest is wave-uniform base + lane*16).
__device__ __forceinline__ void stage_all(const half_t* __restrict__ xh,
                                          const int* __restrict__ nbr,
                                          int base, char* tile, int tid)
{
    const int w = tid >> 6;
    const int lane = tid & 63;
    const int rr = lane >> 4, c = lane & 15;
    const int rowA = w * 4 + rr;          // 0..15
    const int rowB = rowA + 16;           // 16..31  (rowB&7 == rowA&7)
    const int nodeA = base + rowA;
    const int nodeB = base + rowB;
    int4 a4 = ((const int4*)nbr)[nodeA];
    int4 b4 = ((const int4*)nbr)[nodeB];
    int srcA[5] = {nodeA, a4.x, a4.y, a4.z, a4.w};
    int srcB[5] = {nodeB, b4.x, b4.y, b4.z, b4.w};
    const int sw = ((c ^ (rowA & 7)) << 4);
#pragma unroll
    for (int s = 0; s < 5; ++s) {
        const char* gA = (const char*)xh + (size_t)srcA[s] * 256 + sw;
        const char* gB = (const char*)xh + (size_t)srcB[s] * 256 + sw;
        async_copy16(gA, tile + s * 8192 + (w * 4) * 256);
        async_copy16(gB, tile + s * 8192 + (w * 4 + 16) * 256);
    }
}

// --------- fp8 stage: 5 slot-tiles, 128-B rows, 5 DMA instrs/wave -----------
// slot r at r*4096; 16-B chunk kc of row stored at kc^(row&7).
__device__ __forceinline__ void stage_all8(const unsigned char* __restrict__ xq,
                                           const int* __restrict__ nbr,
                                           int base, char* tile, int tid)
{
    const int w = tid >> 6;
    const int lane = tid & 63;
    const int ro = lane >> 3;             // row offset 0..7 within instr
    const int c = lane & 7;               // 16-B chunk 0..7
    const int row = w * 8 + ro;           // 0..31 across 4 waves
    const int node = base + row;
    int4 a4 = ((const int4*)nbr)[node];
    int src[5] = {node, a4.x, a4.y, a4.z, a4.w};
    const int sw = ((c ^ (row & 7)) << 4);
#pragma unroll
    for (int s = 0; s < 5; ++s) {
        const char* g = (const char*)xq + (size_t)src[s] * 128 + sw;
        async_copy16(g, tile + s * 4096 + (w * 8) * 128);
    }
}

// --------------------- A-frag preload: 8 loads ------------------------------
__device__ __forceinline__ void load_af(int mid, const half_t* __restrict__ wph,
                                        int lane, f16x8 (&af)[8])
{
#pragma unroll
    for (int kt = 0; kt < 4; ++kt) {
        af[kt * 2]     = *(const f16x8*)(wph + ((mid * 8 + kt) * 64 + lane) * 8);
        af[kt * 2 + 1] = *(const f16x8*)(wph + ((mid * 8 + 4 + kt) * 64 + lane) * 8);
    }
}

// -------- 32(kout) x 32(node) x 128(d) projection from f16 slot tile --------
__device__ __forceinline__ void proj32(const f16x8 (&af)[8], const half_t* tile,
                                       int lane, f32x4 (&acc)[2][2])
{
    const int l15 = lane & 15, q = lane >> 4;
#pragma unroll
    for (int mt = 0; mt < 2; ++mt)
#pragma unroll
        for (int nt = 0; nt < 2; ++nt)
            acc[mt][nt] = (f32x4){0.f, 0.f, 0.f, 0.f};
#pragma unroll
    for (int kt = 0; kt < 4; ++kt) {
#pragma unroll
        for (int nt = 0; nt < 2; ++nt) {
            int row = nt * 16 + l15;
            int sq = (kt * 4 + q) ^ (row & 7);
            f16x8 b = *(const f16x8*)(tile + row * 128 + sq * 8);
            acc[0][nt] = __builtin_amdgcn_mfma_f32_16x16x32_f16(af[kt * 2], b, acc[0][nt], 0, 0, 0);
            acc[1][nt] = __builtin_amdgcn_mfma_f32_16x16x32_f16(af[kt * 2 + 1], b, acc[1][nt], 0, 0, 0);
        }
    }
}

// ---------- same projection from fp8 slot tile (decode -> f16 MFMA) ---------
__device__ __forceinline__ void proj32q(const f16x8 (&af)[8], const char* tile,
                                        int lane, f32x4 (&acc)[2][2])
{
    const int l15 = lane & 15, q = lane >> 4;
#pragma unroll
    for (int mt = 0; mt < 2; ++mt)
#pragma unroll
        for (int nt = 0; nt < 2; ++nt)
            acc[mt][nt] = (f32x4){0.f, 0.f, 0.f, 0.f};
#pragma unroll
    for (int kt = 0; kt < 4; ++kt) {
#pragma unroll
        for (int nt = 0; nt < 2; ++nt) {
            int row = nt * 16 + l15;
            int kc = kt * 2 + (q >> 1);                    // 16-B chunk 0..7
            uint2 v = *(const uint2*)(tile + row * 128 +
                                      ((kc ^ (row & 7)) << 4) + (q & 1) * 8);
            f16x8 b = dec8(v);
            acc[0][nt] = __builtin_amdgcn_mfma_f32_16x16x32_f16(af[kt * 2], b, acc[0][nt], 0, 0, 0);
            acc[1][nt] = __builtin_amdgcn_mfma_f32_16x16x32_f16(af[kt * 2 + 1], b, acc[1][nt], 0, 0, 0);
        }
    }
}

// ------------- pass A worker: one 32-node group -> 20 atomic sums -----------
__device__ __forceinline__ void sums_group(const char* tile, int bidx,
                                           const half_t* __restrict__ wph,
                                           float* __restrict__ sums_p,
                                           int lane, int h)
{
    f16x8 af[8];
    load_af(h, wph, lane, af);
    f32x4 qf[2][2], kf[2][2];
    proj32q(af, tile, lane, qf);

    float esum[5];
#pragma unroll
    for (int r = 0; r < R; ++r) {
        load_af(4 + h * 5 + r, wph, lane, af);
        proj32q(af, tile + r * 4096, lane, kf);
        float es = 0.f;
#pragma unroll
        for (int nt = 0; nt < 2; ++nt) {
            float p = 0.f;
#pragma unroll
            for (int mt = 0; mt < 2; ++mt)
#pragma unroll
                for (int j = 0; j < 4; ++j)
                    p += qf[mt][nt][j] * kf[mt][nt][j];
            p += __shfl_xor(p, 16, 64);
            p += __shfl_xor(p, 32, 64);
            es += __expf(p * 0.17677669529663688f);
        }
        es += __shfl_xor(es, 1, 64); es += __shfl_xor(es, 2, 64);
        es += __shfl_xor(es, 4, 64); es += __shfl_xor(es, 8, 64);
        esum[r] = es;
    }
#pragma unroll
    for (int r = 0; r < R; ++r)
        if (lane == 0)
            atomicAdd(&sums_p[(h * 5 + r) * 64 + (bidx & 63)], esum[r]);
}

// ----------------- pass A: fp8 gather -> softmax sums only ------------------
// 64 nodes per block as 2x32-node groups; 40960 B LDS -> 4 blocks/CU (R7's
// proven point) at HALF the gathered bytes and requests.
__global__ __launch_bounds__(THREADS, 4)
void knot_sums(const unsigned char* __restrict__ xq, const int* __restrict__ nbr,
               const half_t* __restrict__ wph, float* __restrict__ sums_p)
{
    __shared__ __align__(16) char smem[2 * 5 * 4096];   // 40960 B
    const int g0 = blockIdx.x * 64;
    const int g1 = g0 + 32;
    const int lane = threadIdx.x & 63;
    const int h = __builtin_amdgcn_readfirstlane((int)(threadIdx.x >> 6));
    const bool has2 = (g1 < N_NODES);    // tail: block 1562 has one group

    stage_all8(xq, nbr, g0, smem, threadIdx.x);
    if (has2) stage_all8(xq, nbr, g1, smem + 20480, threadIdx.x);
    __syncthreads();

    sums_group(smem, blockIdx.x, wph, sums_p, lane, h);
    if (has2) sums_group(smem + 20480, blockIdx.x, wph, sums_p, lane, h);
}

// ------- pass B: ONE f16 gather -> Q, K->e, V, 1/S scale, output ------------
#define ZS 132   // zt row stride in floats (16B-aligned)
__global__ __launch_bounds__(THREADS, 4)
void knot_all(const half_t* __restrict__ xh, const int* __restrict__ nbr,
              const half_t* __restrict__ wph, const float* __restrict__ sums_p,
              float* __restrict__ out)
{
    __shared__ __align__(16) char smem[5 * 8192];   // tile; reused as zt
    const int base = blockIdx.x * NPB;
    const int lane = threadIdx.x & 63;
    const int h = __builtin_amdgcn_readfirstlane((int)(threadIdx.x >> 6));
    const int l15 = lane & 15, q = lane >> 4;

    stage_all(xh, nbr, base, smem, threadIdx.x);

    // softmax-sum reduce (hidden under the staging DMAs)
    float inv[5];
#pragma unroll
    for (int r = 0; r < R; ++r) {
        float v = sums_p[(h * 5 + r) * 64 + lane];
        v += __shfl_xor(v, 1, 64);  v += __shfl_xor(v, 2, 64);
        v += __shfl_xor(v, 4, 64);  v += __shfl_xor(v, 8, 64);
        v += __shfl_xor(v, 16, 64); v += __shfl_xor(v, 32, 64);
        inv[r] = 1.0f / v;
    }

    f16x8 af[8];
    load_af(h, wph, lane, af);                       // Q-weights
    __syncthreads();                                 // the ONLY pre-compute barrier

    f32x4 qf[2][2], t[2][2], z[2][2];
    proj32(af, (const half_t*)smem, lane, qf);       // Q on slot-0 tile
#pragma unroll
    for (int mt = 0; mt < 2; ++mt)
#pragma unroll
        for (int nt = 0; nt < 2; ++nt)
            z[mt][nt] = (f32x4){0.f, 0.f, 0.f, 0.f};

#pragma unroll
    for (int r = 0; r < R; ++r) {
        // ---- K_r -> e (f32, never rounded through f16) ----
        load_af(4 + h * 5 + r, wph, lane, af);
        proj32(af, (const half_t*)(smem + r * 8192), lane, t);
        float er[2];
#pragma unroll
        for (int nt = 0; nt < 2; ++nt) {
            float p = 0.f;
#pragma unroll
            for (int mt = 0; mt < 2; ++mt)
#pragma unroll
                for (int j = 0; j < 4; ++j)
                    p += qf[mt][nt][j] * t[mt][nt][j];
            p += __shfl_xor(p, 16, 64);
            p += __shfl_xor(p, 32, 64);
            er[nt] = __expf(p * 0.17677669529663688f);
        }
        // ---- V_r -> z += (e*inv) * V ----
        load_af(24 + h * 5 + r, wph, lane, af);
        proj32(af, (const half_t*)(smem + r * 8192), lane, t);
#pragma unroll
        for (int nt = 0; nt < 2; ++nt) {
            float w = er[nt] * inv[r];
#pragma unroll
            for (int mt = 0; mt < 2; ++mt)
#pragma unroll
                for (int j = 0; j < 4; ++j)
                    z[mt][nt][j] += w * t[mt][nt][j];
        }
    }

    // ---- epilogue: node-major zt[32][ZS], float4 writes, coalesced reads ----
    __syncthreads();
    float* zt = (float*)smem;
#pragma unroll
    for (int mt = 0; mt < 2; ++mt)
#pragma unroll
        for (int nt = 0; nt < 2; ++nt) {
            int node = nt * 16 + l15;
            int col = h * 32 + mt * 16 + q * 4;      // j contiguous -> f32x4
            *(f32x4*)(zt + node * ZS + col) = z[mt][nt];
        }
    __syncthreads();
    {
        const int row = threadIdx.x >> 3;            // 0..31
        const int c = threadIdx.x & 7;               // 0..7
        float* dst = out + (size_t)(base + row) * D + c * 16;
        const float* srcp = zt + row * ZS + c * 16;
#pragma unroll
        for (int i4 = 0; i4 < 4; ++i4)
            *(float4*)(dst + i4 * 4) = *(const float4*)(srcp + i4 * 4);
    }
}

// --------------------------------- launcher ---------------------------------
// ws (bytes): [0,5120) sums_p | [4194304,+360448) wph
//             [4718592,+25.6e6) xh | [30408704,+12.8e6) xq     ~43.2 MB
extern "C" void kernel_launch(void* const* d_in, const int* in_sizes, int n_in,
                              void* d_out, int out_size, void* d_ws, size_t ws_size,
                              hipStream_t stream)
{
    const float* x   = (const float*)d_in[0];
    const int*   nbr = (const int*)d_in[1];
    const float* w_q = (const float*)d_in[2];
    const float* w_k = (const float*)d_in[3];
    const float* w_v = (const float*)d_in[4];
    float* out = (float*)d_out;

    float*         sums_p = (float*)d_ws;
    half_t*        wph    = (half_t*)((char*)d_ws + 4194304);
    half_t*        xh     = (half_t*)((char*)d_ws + 4718592);
    unsigned char* xq     = (unsigned char*)d_ws + 30408704;

    prep<<<44 + 2048, THREADS, 0, stream>>>(x, w_q, w_k, w_v, xh, xq, wph, sums_p);
    knot_sums<<<(N_NODES + 63) / 64, THREADS, 0, stream>>>(xq, nbr, wph, sums_p);
    knot_all<<<NBLOCKS, THREADS, 0, stream>>>(xh, nbr, wph, sums_p, out);
}

// Round 4
// 184.988 us; speedup vs baseline: 1.6361x; 1.6361x over previous
//
#include <hip/hip_runtime.h>

// KnotAttention MI355X — round 11: re-anchor at the verified R7 optimum.
//
// R8 (Y=e*V materialize): 211us — 256 MB streaming > 62 MB miss-traffic saved.
// R9 (occupancy 34->75%): 256us — more concurrent streams = more L2 misses.
// R10 (fp8 gather): 302us — miss granularity >= row size; halving row bytes
//   does not halve random line-touches.
// Unified model from R7/R9/R10 counters: gather-pass duration = L2-miss
// bytes / ~1.1 TB/s (per-XCD L2<->L3 fabric service, ~150 GB/s/XCD). The
// two passes are mandatory (softmax-over-nodes couples S globally; tiles
// cannot persist: 128 MB needed vs 40 MB LDS; any materialized intermediate
// is >= 128 MB > the ~62 MB it saves). R7 sits on this floor:
// 2 x 62 MB / 1.1 TB/s ~= 105us gather + ~15us prep + fixed overhead.
//
// This file is the verified 184.4us R7 kernel, byte-for-byte.

#define N_NODES 100000
#define D 128
#define H 4
#define R 5
#define NPB 32
#define THREADS 256
#define NBLOCKS (N_NODES / NPB)   // 3125

typedef _Float16 half_t;
typedef __attribute__((ext_vector_type(2))) _Float16 f16x2;
typedef __attribute__((ext_vector_type(8))) _Float16 f16x8;
typedef __attribute__((ext_vector_type(4))) float f32x4;

typedef const __attribute__((address_space(1))) unsigned int* gp_t;
typedef __attribute__((address_space(3))) unsigned int* lp_t;

__device__ __forceinline__ void async_copy16(const void* g, void* l) {
    __builtin_amdgcn_global_load_lds((gp_t)g, (lp_t)l, 16, 0, 0);
}

// ------------- prep: weights -> A-frags, x -> f16, zero sums_p --------------
__global__ void prep(const float* __restrict__ x,
                     const float* __restrict__ wq, const float* __restrict__ wk,
                     const float* __restrict__ wv,
                     half_t* __restrict__ xh, half_t* __restrict__ wph,
                     float* __restrict__ sums_p)
{
    const int bid = blockIdx.x;
    const int t = threadIdx.x;
    if (bid < 44) {
        const float* src = (bid < 4) ? (wq + bid * 4096)
                         : (bid < 24) ? (wk + (bid - 4) * 4096)
                                      : (wv + (bid - 24) * 4096);
#pragma unroll
        for (int i = 0; i < 16; ++i) {
            int p = t * 16 + i;
            int j = p & 7, ln = (p >> 3) & 63, f = p >> 9;
            int kt = f & 3, mt = f >> 2;
            int d = kt * 32 + (ln >> 4) * 8 + j;
            int ko = mt * 16 + (ln & 15);
            wph[bid * 4096 + p] = (half_t)src[d * 32 + ko];
        }
    } else {
        if (bid == 44) {
            for (int i = t; i < 1280; i += THREADS) sums_p[i] = 0.f;
        }
        const int total = N_NODES * D / 8;
        const int nb = gridDim.x - 44;
        for (int i = (bid - 44) * THREADS + t; i < total; i += nb * THREADS) {
            const float4* s = (const float4*)x + (size_t)i * 2;
            float4 a = s[0], b = s[1];
            f16x8 h8 = {(half_t)a.x, (half_t)a.y, (half_t)a.z, (half_t)a.w,
                        (half_t)b.x, (half_t)b.y, (half_t)b.z, (half_t)b.w};
            *((f16x8*)xh + i) = h8;
        }
    }
}

// ---------- one burst: stage all 5 slot-tiles (10 DMA instrs/wave) ----------
// tile layout: slot r at r*8192; row stride 256 B; 16-B quad kq of row stored
// at kq^(row&7) (swizzle folded into the GLOBAL address; LDS dest is
// wave-uniform base + lane*16 as HW requires).
__device__ __forceinline__ void stage_all(const half_t* __restrict__ xh,
                                          const int* __restrict__ nbr,
                                          int base, char* tile, int tid)
{
    const int w = tid >> 6;
    const int lane = tid & 63;
    const int rr = lane >> 4, c = lane & 15;
    const int rowA = w * 4 + rr;          // 0..15
    const int rowB = rowA + 16;           // 16..31  (rowB&7 == rowA&7)
    const int nodeA = base + rowA;
    const int nodeB = base + rowB;
    int4 a4 = ((const int4*)nbr)[nodeA];
    int4 b4 = ((const int4*)nbr)[nodeB];
    int srcA[5] = {nodeA, a4.x, a4.y, a4.z, a4.w};
    int srcB[5] = {nodeB, b4.x, b4.y, b4.z, b4.w};
    const int sw = ((c ^ (rowA & 7)) << 4);
#pragma unroll
    for (int s = 0; s < 5; ++s) {
        const char* gA = (const char*)xh + (size_t)srcA[s] * 256 + sw;
        const char* gB = (const char*)xh + (size_t)srcB[s] * 256 + sw;
        async_copy16(gA, tile + s * 8192 + (w * 4) * 256);
        async_copy16(gB, tile + s * 8192 + (w * 4 + 16) * 256);
    }
}

// --------------------- A-frag preload: 8 loads ------------------------------
__device__ __forceinline__ void load_af(int mid, const half_t* __restrict__ wph,
                                        int lane, f16x8 (&af)[8])
{
#pragma unroll
    for (int kt = 0; kt < 4; ++kt) {
        af[kt * 2]     = *(const f16x8*)(wph + ((mid * 8 + kt) * 64 + lane) * 8);
        af[kt * 2 + 1] = *(const f16x8*)(wph + ((mid * 8 + 4 + kt) * 64 + lane) * 8);
    }
}

// -------- 32(kout) x 32(node) x 128(d) projection from LDS slot tile --------
__device__ __forceinline__ void proj32(const f16x8 (&af)[8], const half_t* tile,
                                       int lane, f32x4 (&acc)[2][2])
{
    const int l15 = lane & 15, q = lane >> 4;
#pragma unroll
    for (int mt = 0; mt < 2; ++mt)
#pragma unroll
        for (int nt = 0; nt < 2; ++nt)
            acc[mt][nt] = (f32x4){0.f, 0.f, 0.f, 0.f};
#pragma unroll
    for (int kt = 0; kt < 4; ++kt) {
#pragma unroll
        for (int nt = 0; nt < 2; ++nt) {
            int row = nt * 16 + l15;
            int sq = (kt * 4 + q) ^ (row & 7);
            f16x8 b = *(const f16x8*)(tile + row * 128 + sq * 8);
            acc[0][nt] = __builtin_amdgcn_mfma_f32_16x16x32_f16(af[kt * 2], b, acc[0][nt], 0, 0, 0);
            acc[1][nt] = __builtin_amdgcn_mfma_f32_16x16x32_f16(af[kt * 2 + 1], b, acc[1][nt], 0, 0, 0);
        }
    }
}

// --------------------------- kernel 1: Q,K -> e, sums ------------------------
__global__ __launch_bounds__(THREADS, 4)
void knot_logits(const half_t* __restrict__ xh, const int* __restrict__ nbr,
                 const half_t* __restrict__ wph,
                 half_t* __restrict__ eh, float* __restrict__ sums_p)
{
    __shared__ __align__(16) char smem[5 * 8192];   // 40960 B exactly
    const int base = blockIdx.x * NPB;
    const int lane = threadIdx.x & 63;
    const int h = __builtin_amdgcn_readfirstlane((int)(threadIdx.x >> 6));
    const int l15 = lane & 15, q = lane >> 4;

    stage_all(xh, nbr, base, smem, threadIdx.x);

    f16x8 af[8];
    load_af(h, wph, lane, af);                       // Q-weights (mat h)
    __syncthreads();                                 // the ONLY pre-compute barrier

    f32x4 qf[2][2], kf[2][2];
    proj32(af, (const half_t*)smem, lane, qf);       // Q on slot-0 tile

    f16x2 epk[5];
    float esum[5];
#pragma unroll
    for (int r = 0; r < R; ++r) {
        load_af(4 + h * 5 + r, wph, lane, af);
        proj32(af, (const half_t*)(smem + r * 8192), lane, kf);

        float es = 0.f;
#pragma unroll
        for (int nt = 0; nt < 2; ++nt) {
            float p = 0.f;
#pragma unroll
            for (int mt = 0; mt < 2; ++mt)
#pragma unroll
                for (int j = 0; j < 4; ++j)
                    p += qf[mt][nt][j] * kf[mt][nt][j];
            p += __shfl_xor(p, 16, 64);
            p += __shfl_xor(p, 32, 64);
            float e = __expf(p * 0.17677669529663688f);
            epk[r][nt] = (half_t)e;
            es += e;
        }
        es += __shfl_xor(es, 1, 64); es += __shfl_xor(es, 2, 64);
        es += __shfl_xor(es, 4, 64); es += __shfl_xor(es, 8, 64);
        esum[r] = es;    // summed over l15; q-copies identical (q==0 atomics)
    }

    // deferred flush
#pragma unroll
    for (int r = 0; r < R; ++r) {
        if (q == 0) {
#pragma unroll
            for (int nt = 0; nt < 2; ++nt)
                eh[(size_t)(h * 5 + r) * N_NODES + base + nt * 16 + l15] = epk[r][nt];
        }
        if (lane == 0)
            atomicAdd(&sums_p[(h * 5 + r) * 64 + (blockIdx.x & 63)], esum[r]);
    }
}

// --------------------------- kernel 2: V -> Z -> out -------------------------
#define ZS 132   // zt row stride in floats (16B-aligned, reads ~conflict-free)
__global__ __launch_bounds__(THREADS, 4)
void knot_out(const half_t* __restrict__ xh, const int* __restrict__ nbr,
              const half_t* __restrict__ wph, const half_t* __restrict__ eh,
              const float* __restrict__ sums_p, float* __restrict__ out)
{
    __shared__ __align__(16) char smem[5 * 8192];   // tile; reused as zt
    const int base = blockIdx.x * NPB;
    const int lane = threadIdx.x & 63;
    const int h = __builtin_amdgcn_readfirstlane((int)(threadIdx.x >> 6));
    const int l15 = lane & 15, q = lane >> 4;

    stage_all(xh, nbr, base, smem, threadIdx.x);

    // register-only softmax-sum reduce (full 64-lane xor => broadcast)
    float inv[5];
#pragma unroll
    for (int r = 0; r < R; ++r) {
        float v = sums_p[(h * 5 + r) * 64 + lane];
        v += __shfl_xor(v, 1, 64);  v += __shfl_xor(v, 2, 64);
        v += __shfl_xor(v, 4, 64);  v += __shfl_xor(v, 8, 64);
        v += __shfl_xor(v, 16, 64); v += __shfl_xor(v, 32, 64);
        inv[r] = 1.0f / v;
    }
    float ev[5][2];
#pragma unroll
    for (int r = 0; r < R; ++r)
#pragma unroll
        for (int nt = 0; nt < 2; ++nt)
            ev[r][nt] = (float)eh[(size_t)(h * 5 + r) * N_NODES + base + nt * 16 + l15];

    f16x8 af[8];
    load_af(24 + h * 5 + 0, wph, lane, af);
    __syncthreads();                                 // the ONLY pre-compute barrier

    f32x4 z[2][2], vf[2][2];
#pragma unroll
    for (int mt = 0; mt < 2; ++mt)
#pragma unroll
        for (int nt = 0; nt < 2; ++nt)
            z[mt][nt] = (f32x4){0.f, 0.f, 0.f, 0.f};

#pragma unroll
    for (int r = 0; r < R; ++r) {
        proj32(af, (const half_t*)(smem + r * 8192), lane, vf);
        if (r < R - 1) load_af(24 + h * 5 + r + 1, wph, lane, af);
#pragma unroll
        for (int nt = 0; nt < 2; ++nt) {
            float w = ev[r][nt] * inv[r];
#pragma unroll
            for (int mt = 0; mt < 2; ++mt)
#pragma unroll
                for (int j = 0; j < 4; ++j)
                    z[mt][nt][j] += w * vf[mt][nt][j];
        }
    }

    // ---- epilogue: node-major zt[32][ZS], float4 writes, coalesced reads ----
    __syncthreads();
    float* zt = (float*)smem;
#pragma unroll
    for (int mt = 0; mt < 2; ++mt)
#pragma unroll
        for (int nt = 0; nt < 2; ++nt) {
            int node = nt * 16 + l15;
            int col = h * 32 + mt * 16 + q * 4;      // j contiguous -> f32x4
            *(f32x4*)(zt + node * ZS + col) = z[mt][nt];
        }
    __syncthreads();
    {
        const int row = threadIdx.x >> 3;            // 0..31
        const int c = threadIdx.x & 7;               // 0..7
        float* dst = out + (size_t)(base + row) * D + c * 16;
        const float* srcp = zt + row * ZS + c * 16;
#pragma unroll
        for (int i4 = 0; i4 < 4; ++i4)
            *(float4*)(dst + i4 * 4) = *(const float4*)(srcp + i4 * 4);
    }
}

// --------------------------------- launcher ---------------------------------
// ws (bytes): [0,5120) sums_p | [8192,+4e6) eh f16[20*N]
//             [4194304,+360448) wph | [4718592,+25.6e6) xh     ~30.3 MB
extern "C" void kernel_launch(void* const* d_in, const int* in_sizes, int n_in,
                              void* d_out, int out_size, void* d_ws, size_t ws_size,
                              hipStream_t stream)
{
    const float* x   = (const float*)d_in[0];
    const int*   nbr = (const int*)d_in[1];
    const float* w_q = (const float*)d_in[2];
    const float* w_k = (const float*)d_in[3];
    const float* w_v = (const float*)d_in[4];
    float* out = (float*)d_out;

    float*  sums_p = (float*)d_ws;
    half_t* eh     = (half_t*)((char*)d_ws + 8192);
    half_t* wph    = (half_t*)((char*)d_ws + 4194304);
    half_t* xh     = (half_t*)((char*)d_ws + 4718592);

    prep<<<44 + 2048, THREADS, 0, stream>>>(x, w_q, w_k, w_v, xh, wph, sums_p);
    knot_logits<<<NBLOCKS, THREADS, 0, stream>>>(xh, nbr, wph, eh, sums_p);
    knot_out<<<NBLOCKS, THREADS, 0, stream>>>(xh, nbr, wph, eh, sums_p, out);
}